// Round 1
// baseline (26411.642 us; speedup 1.0000x reference)
//
#include <hip/hip_runtime.h>
#include <cstddef>
#include <cstdint>

#define HID   1024
#define BATCH 64
#define TSEQ  512
#define NB    (BATCH*HID)     // 65536 floats per [B,H] slab
#define NBLK  192
#define KC    128
#define NITER 514

// ---------------------------------------------------------------------------
// ws layout (floats):
//  [0*NB, 2*NB)  h0 ping-pong   (slot t&1 holds h0[t])
//  [2*NB, 4*NB)  h1 ping-pong   (slot t&1 holds h1[t])
//  [4*NB, 6*NB)  ig1 ping-pong  (slot t&1 holds igate1[t] + bx1 + bh1)
//  [6*NB]        barrier counter (unsigned, zeroed by kernel A)
// ---------------------------------------------------------------------------

// Grid barrier: monotonic counter, device scope (cross-XCD safe: release RMW
// writes back L2, acquire fence invalidates stale lines). Spin uses relaxed
// agent loads (no repeated cache invalidation while polling).
__device__ __forceinline__ void gbar(unsigned* bar, unsigned target) {
  __syncthreads();
  if (threadIdx.x == 0) {
    __hip_atomic_fetch_add(bar, 1u, __ATOMIC_RELEASE, __HIP_MEMORY_SCOPE_AGENT);
    while (__hip_atomic_load(bar, __ATOMIC_RELAXED, __HIP_MEMORY_SCOPE_AGENT) < target) {
      __builtin_amdgcn_s_sleep(1);
    }
    __builtin_amdgcn_fence(__ATOMIC_ACQUIRE, "agent");
  }
  __syncthreads();
}

// ---------------------------------------------------------------------------
// Kernel A: bulk Igate0 = X @ Wx0^T + bx0 + bh0  -> written into d_out[0..T*NB)
// Classic 64x64 tile, BK=16, 256 threads, 4x4 micro-tile. Also zeroes barrier.
// ---------------------------------------------------------------------------
__global__ __launch_bounds__(256) void igate0_gemm(
    const float* __restrict__ X, const float* __restrict__ Wx,
    const float* __restrict__ bx, const float* __restrict__ bh,
    float* __restrict__ ig_out, float* __restrict__ ws)
{
  if (blockIdx.x == 0 && threadIdx.x == 0) {
    *(unsigned*)(ws + (size_t)6*NB) = 0u;
  }
  __shared__ __align__(16) float asT[16][68];
  __shared__ __align__(16) float wsT[16][68];
  const int tid = threadIdx.x;
  const int mt = blockIdx.x >> 4;          // 512 m-tiles
  const int nt = blockIdx.x & 15;          // 16 n-tiles
  const int m0 = mt * 64, n0 = nt * 64;
  const int lr = tid >> 2;                 // load row 0..63
  const int lk = (tid & 3) * 4;            // load k offset 0,4,8,12
  const int tm = (tid & 15) * 4;           // micro-tile row base
  const int tn = (tid >> 4) * 4;           // micro-tile col base
  float acc[4][4] = {};

  for (int k0 = 0; k0 < HID; k0 += 16) {
    float4 av = *(const float4*)&X [(size_t)(m0 + lr) * HID + k0 + lk];
    float4 wv = *(const float4*)&Wx[(size_t)(n0 + lr) * HID + k0 + lk];
    __syncthreads();
    asT[lk+0][lr] = av.x; asT[lk+1][lr] = av.y; asT[lk+2][lr] = av.z; asT[lk+3][lr] = av.w;
    wsT[lk+0][lr] = wv.x; wsT[lk+1][lr] = wv.y; wsT[lk+2][lr] = wv.z; wsT[lk+3][lr] = wv.w;
    __syncthreads();
#pragma unroll
    for (int kk = 0; kk < 16; ++kk) {
      float4 a4 = *(const float4*)&asT[kk][tm];
      float4 w4 = *(const float4*)&wsT[kk][tn];
      acc[0][0] += a4.x*w4.x; acc[0][1] += a4.x*w4.y; acc[0][2] += a4.x*w4.z; acc[0][3] += a4.x*w4.w;
      acc[1][0] += a4.y*w4.x; acc[1][1] += a4.y*w4.y; acc[1][2] += a4.y*w4.z; acc[1][3] += a4.y*w4.w;
      acc[2][0] += a4.z*w4.x; acc[2][1] += a4.z*w4.y; acc[2][2] += a4.z*w4.z; acc[2][3] += a4.z*w4.w;
      acc[3][0] += a4.w*w4.x; acc[3][1] += a4.w*w4.y; acc[3][2] += a4.w*w4.z; acc[3][3] += a4.w*w4.w;
    }
  }

#pragma unroll
  for (int i = 0; i < 4; ++i) {
    const int m = m0 + tm + i;
    const int n = n0 + tn;
    float4 o;
    o.x = acc[i][0] + bx[n+0] + bh[n+0];
    o.y = acc[i][1] + bx[n+1] + bh[n+1];
    o.z = acc[i][2] + bx[n+2] + bh[n+2];
    o.w = acc[i][3] + bx[n+3] + bh[n+3];
    *(float4*)&ig_out[(size_t)m * HID + n] = o;
  }
}

// ---------------------------------------------------------------------------
// Kernel B: persistent cooperative pipelined recurrence.
// 192 blocks x 256 threads. Roles (by blk>>6):
//   0: h0[t=i]      = tanh(ig0[i] + h0_prev @ Wh0^T)            (ig0 pre-biased)
//   1: ig1[t=i-1]   = h0[i-1] @ Wx1^T + bx1 + bh1
//   2: h1[t=i-2]    = tanh(ig1[i-2] + h1_prev @ Wh1^T); out = 10*h1
// One grid barrier per iteration. Dot engine: h staged transposed in LDS
// (hsT[k][b], pad 65 -> 2-way bank alias = free); W rows via wave-uniform
// scalar loads (cols forced uniform through readfirstlane).
// ---------------------------------------------------------------------------
__global__ __launch_bounds__(256) void rnn_step(
    float* io,                         // d_out: ig0 source AND output sink
    const float* __restrict__ h0_init, // [2][B][H]
    const float* __restrict__ Wh0,
    const float* __restrict__ Wx1,
    const float* __restrict__ Wh1,
    const float* __restrict__ bx1,
    const float* __restrict__ bh1,
    float* __restrict__ ws)
{
  __shared__ float hsT[KC][65];
  const int tid  = threadIdx.x;
  const int blk  = blockIdx.x;
  const int role = blk >> 6;                 // 0,1,2
  const int c0   = (blk & 63) << 4;          // 16 cols per block
  const int b    = tid & 63;
  const int cq   = __builtin_amdgcn_readfirstlane(tid >> 6); // wave-uniform
  const int c    = c0 + cq * 4;

  float* h0s[2]  = { ws,          ws + NB     };
  float* h1s[2]  = { ws + 2*NB,   ws + 3*NB   };
  float* ig1s[2] = { ws + 4*(size_t)NB, ws + 5*(size_t)NB };
  unsigned* bar  = (unsigned*)(ws + 6*(size_t)NB);

  const float* W = (role == 0) ? Wh0 : (role == 1) ? Wx1 : Wh1;
  const float* __restrict__ Wr0 = W + (size_t)(c + 0) * HID;
  const float* __restrict__ Wr1 = W + (size_t)(c + 1) * HID;
  const float* __restrict__ Wr2 = W + (size_t)(c + 2) * HID;
  const float* __restrict__ Wr3 = W + (size_t)(c + 3) * HID;

  for (int i = 0; i < NITER; ++i) {
    bool active;
    const float* src;
    if (role == 0)      { active = (i <= 511);            src = (i == 0) ? h0_init        : h0s[(i-1) & 1]; }
    else if (role == 1) { active = (i >= 1 && i <= 512);  src = h0s[(i-1) & 1]; }
    else                { active = (i >= 2 && i <= 513);  src = (i == 2) ? (h0_init + NB) : h1s[(i-3) & 1]; }

    if (active) {
      float a0 = 0.f, a1 = 0.f, a2 = 0.f, a3 = 0.f;
      float4 pf[8];
#pragma unroll
      for (int r = 0; r < 8; ++r) {
        const int f = r * 256 + tid, bb = f >> 5, jq = f & 31;
        pf[r] = *(const float4*)&src[(size_t)bb * HID + jq * 4];
      }
      for (int kc = 0; kc < HID / KC; ++kc) {
        __syncthreads();
#pragma unroll
        for (int r = 0; r < 8; ++r) {
          const int f = r * 256 + tid, bb = f >> 5, jq = f & 31;
          hsT[jq*4+0][bb] = pf[r].x;
          hsT[jq*4+1][bb] = pf[r].y;
          hsT[jq*4+2][bb] = pf[r].z;
          hsT[jq*4+3][bb] = pf[r].w;
        }
        float4 nf[8];
        if (kc + 1 < HID / KC) {
#pragma unroll
          for (int r = 0; r < 8; ++r) {
            const int f = r * 256 + tid, bb = f >> 5, jq = f & 31;
            nf[r] = *(const float4*)&src[(size_t)bb * HID + (kc + 1) * KC + jq * 4];
          }
        }
        __syncthreads();
        const float* w0 = Wr0 + kc * KC;
        const float* w1 = Wr1 + kc * KC;
        const float* w2 = Wr2 + kc * KC;
        const float* w3 = Wr3 + kc * KC;
#pragma unroll 16
        for (int j = 0; j < KC; ++j) {
          const float hv = hsT[j][b];
          a0 += hv * w0[j];
          a1 += hv * w1[j];
          a2 += hv * w2[j];
          a3 += hv * w3[j];
        }
        if (kc + 1 < HID / KC) {
#pragma unroll
          for (int r = 0; r < 8; ++r) pf[r] = nf[r];
        }
      }

      const size_t rb = (size_t)b * HID + c;
      if (role == 0) {
        const size_t ob = (size_t)i * NB + rb;
        float* dst = h0s[i & 1];
        dst[rb+0] = tanhf(a0 + io[ob+0]);
        dst[rb+1] = tanhf(a1 + io[ob+1]);
        dst[rb+2] = tanhf(a2 + io[ob+2]);
        dst[rb+3] = tanhf(a3 + io[ob+3]);
      } else if (role == 1) {
        float* dst = ig1s[(i-1) & 1];
        dst[rb+0] = a0 + bx1[c+0] + bh1[c+0];
        dst[rb+1] = a1 + bx1[c+1] + bh1[c+1];
        dst[rb+2] = a2 + bx1[c+2] + bh1[c+2];
        dst[rb+3] = a3 + bx1[c+3] + bh1[c+3];
      } else {
        const int t = i - 2;                  // t&1 == i&1
        const float* ig = ig1s[i & 1];
        float* dst = h1s[i & 1];
        const size_t ob = (size_t)t * NB + rb;
        float t0 = tanhf(a0 + ig[rb+0]);
        float t1 = tanhf(a1 + ig[rb+1]);
        float t2 = tanhf(a2 + ig[rb+2]);
        float t3 = tanhf(a3 + ig[rb+3]);
        dst[rb+0] = t0; dst[rb+1] = t1; dst[rb+2] = t2; dst[rb+3] = t3;
        io[ob+0] = 10.f*t0; io[ob+1] = 10.f*t1; io[ob+2] = 10.f*t2; io[ob+3] = 10.f*t3;
      }
    }
    gbar(bar, (unsigned)(NBLK * (i + 1)));
  }
}

// ---------------------------------------------------------------------------
// Kernel C: write h_n = [h0[511], h1[511]] (both live in ping-pong slot 1).
// ---------------------------------------------------------------------------
__global__ __launch_bounds__(256) void finalize_hn(
    const float* __restrict__ ws, float* __restrict__ out)
{
  const int g = blockIdx.x * 256 + threadIdx.x;     // 0..131071
  const float* h0f = ws + NB;                       // h0 slot 1
  const float* h1f = ws + 3 * (size_t)NB;           // h1 slot 1
  const float v = (g < NB) ? h0f[g] : h1f[g - NB];
  out[(size_t)TSEQ * NB + g] = v;
}

// ---------------------------------------------------------------------------
extern "C" void kernel_launch(void* const* d_in, const int* in_sizes, int n_in,
                              void* d_out, int out_size, void* d_ws, size_t ws_size,
                              hipStream_t stream) {
  const float* x  = (const float*)d_in[0];
  const float* h0 = (const float*)d_in[1];
  const float* Wx = (const float*)d_in[2];
  const float* bx = (const float*)d_in[3];
  const float* Wh = (const float*)d_in[4];
  const float* bh = (const float*)d_in[5];
  float* out = (float*)d_out;
  float* ws  = (float*)d_ws;

  // Bulk igate0 (+both layer-0 biases) into d_out; zeroes barrier counter.
  igate0_gemm<<<dim3(512 * 16), dim3(256), 0, stream>>>(x, Wx, bx, bh, out, ws);

  // Persistent pipelined recurrence (cooperative: needs co-residency).
  float* io = out;
  const float* h0i  = h0;
  const float* pWh0 = Wh;
  const float* pWx1 = Wx + (size_t)HID * HID;
  const float* pWh1 = Wh + (size_t)HID * HID;
  const float* pbx1 = bx + HID;
  const float* pbh1 = bh + HID;
  float* pws = ws;
  void* args[] = { &io, &h0i, &pWh0, &pWx1, &pWh1, &pbx1, &pbh1, &pws };
  hipLaunchCooperativeKernel((const void*)rnn_step, dim3(NBLK), dim3(256),
                             args, 0, stream);

  // h_n tail.
  finalize_hn<<<dim3(512), dim3(256), 0, stream>>>(ws, out);
}

// Round 2
// 17553.888 us; speedup vs baseline: 1.5046x; 1.5046x over previous
//
#include <hip/hip_runtime.h>
#include <cstddef>
#include <cstdint>

#define HID     1024
#define BATCH   64
#define TSEQ    512
#define NB      (BATCH*HID)     // 65536 floats per [B,H] slab
#define NBLK    192
#define NITER   514
#define RSTRIDE 20              // LDS reduction row stride (16 + pad 4)

// ---------------------------------------------------------------------------
// ws layout (floats):
//  [0*NB, 2*NB)  h0 ping-pong   (slot t&1 holds h0[t])
//  [2*NB, 4*NB)  h1 ping-pong   (slot t&1 holds h1[t])
//  [4*NB, 6*NB)  ig1 ping-pong  (slot t&1 holds igate1[t] + bx1 + bh1)
//  [6*NB]        barrier counter (unsigned, zeroed by kernel A)
// ---------------------------------------------------------------------------

__device__ __forceinline__ void gbar(unsigned* bar, unsigned target) {
  __syncthreads();
  if (threadIdx.x == 0) {
    __hip_atomic_fetch_add(bar, 1u, __ATOMIC_RELEASE, __HIP_MEMORY_SCOPE_AGENT);
    while (__hip_atomic_load(bar, __ATOMIC_RELAXED, __HIP_MEMORY_SCOPE_AGENT) < target) {
      __builtin_amdgcn_s_sleep(1);
    }
    __builtin_amdgcn_fence(__ATOMIC_ACQUIRE, "agent");
  }
  __syncthreads();
}

// ---------------------------------------------------------------------------
// Kernel A: bulk Igate0 = X @ Wx0^T + bx0 + bh0  -> written into d_out[0..T*NB)
// ---------------------------------------------------------------------------
__global__ __launch_bounds__(256) void igate0_gemm(
    const float* __restrict__ X, const float* __restrict__ Wx,
    const float* __restrict__ bx, const float* __restrict__ bh,
    float* __restrict__ ig_out, float* __restrict__ ws)
{
  if (blockIdx.x == 0 && threadIdx.x == 0) {
    *(unsigned*)(ws + (size_t)6*NB) = 0u;
  }
  __shared__ __align__(16) float asT[16][68];
  __shared__ __align__(16) float wsT[16][68];
  const int tid = threadIdx.x;
  const int mt = blockIdx.x >> 4;
  const int nt = blockIdx.x & 15;
  const int m0 = mt * 64, n0 = nt * 64;
  const int lr = tid >> 2;
  const int lk = (tid & 3) * 4;
  const int tm = (tid & 15) * 4;
  const int tn = (tid >> 4) * 4;
  float acc[4][4] = {};

  for (int k0 = 0; k0 < HID; k0 += 16) {
    float4 av = *(const float4*)&X [(size_t)(m0 + lr) * HID + k0 + lk];
    float4 wv = *(const float4*)&Wx[(size_t)(n0 + lr) * HID + k0 + lk];
    __syncthreads();
    asT[lk+0][lr] = av.x; asT[lk+1][lr] = av.y; asT[lk+2][lr] = av.z; asT[lk+3][lr] = av.w;
    wsT[lk+0][lr] = wv.x; wsT[lk+1][lr] = wv.y; wsT[lk+2][lr] = wv.z; wsT[lk+3][lr] = wv.w;
    __syncthreads();
#pragma unroll
    for (int kk = 0; kk < 16; ++kk) {
      float4 a4 = *(const float4*)&asT[kk][tm];
      float4 w4 = *(const float4*)&wsT[kk][tn];
      acc[0][0] += a4.x*w4.x; acc[0][1] += a4.x*w4.y; acc[0][2] += a4.x*w4.z; acc[0][3] += a4.x*w4.w;
      acc[1][0] += a4.y*w4.x; acc[1][1] += a4.y*w4.y; acc[1][2] += a4.y*w4.z; acc[1][3] += a4.y*w4.w;
      acc[2][0] += a4.z*w4.x; acc[2][1] += a4.z*w4.y; acc[2][2] += a4.z*w4.z; acc[2][3] += a4.z*w4.w;
      acc[3][0] += a4.w*w4.x; acc[3][1] += a4.w*w4.y; acc[3][2] += a4.w*w4.z; acc[3][3] += a4.w*w4.w;
    }
  }

#pragma unroll
  for (int i = 0; i < 4; ++i) {
    const int m = m0 + tm + i;
    const int n = n0 + tn;
    float4 o;
    o.x = acc[i][0] + bx[n+0] + bh[n+0];
    o.y = acc[i][1] + bx[n+1] + bh[n+1];
    o.z = acc[i][2] + bx[n+2] + bh[n+2];
    o.w = acc[i][3] + bx[n+3] + bh[n+3];
    *(float4*)&ig_out[(size_t)m * HID + n] = o;
  }
}

// ---------------------------------------------------------------------------
// Kernel B: persistent cooperative pipelined recurrence.
// 192 blocks x 512 threads. Roles (by blk>>6):
//   0: h0[t=i]      = tanh(ig0[i] + h0_prev @ Wh0^T)            (ig0 pre-biased)
//   1: ig1[t=i-1]   = h0[i-1] @ Wx1^T + bx1 + bh1
//   2: h1[t=i-2]    = tanh(ig1[i-2] + h1_prev @ Wh1^T); out = 10*h1
//
// Dot engine (no LDS on the hot path):
//   thread = (b = lane 0..63, kq = wave 0..7). Each thread owns all 16 block
//   columns over a private K-slice of 128: h values are thread-private ->
//   register-resident via global dwordx4 loads (chunk double-buffered);
//   W addresses are wave-uniform (readfirstlane kq) -> scalar s_load on the
//   SMEM pipe (64 KB/block, same lines every iter -> per-XCD L2 resident).
//   8 kq-partials reduced through a small padded LDS buffer at the end.
// ---------------------------------------------------------------------------
__global__ __launch_bounds__(512) void rnn_step(
    float* io,                         // d_out: ig0 source AND output sink
    const float* __restrict__ h0_init, // [2][B][H]
    const float* __restrict__ Wh0,
    const float* __restrict__ Wx1,
    const float* __restrict__ Wh1,
    const float* __restrict__ bx1,
    const float* __restrict__ bh1,
    float* __restrict__ ws)
{
  __shared__ __align__(16) float red[8 * 64 * RSTRIDE];   // 40 KB
  const int tid  = threadIdx.x;
  const int blk  = blockIdx.x;
  const int role = blk >> 6;                 // 0,1,2
  const int c0   = (blk & 63) << 4;          // 16 cols per block
  const int b    = tid & 63;
  const int kq   = __builtin_amdgcn_readfirstlane(tid >> 6); // wave id 0..7

  float* h0s[2]  = { ws,                ws + (size_t)NB   };
  float* h1s[2]  = { ws + 2*(size_t)NB, ws + 3*(size_t)NB };
  float* ig1s[2] = { ws + 4*(size_t)NB, ws + 5*(size_t)NB };
  unsigned* bar  = (unsigned*)(ws + 6*(size_t)NB);

  const float* W  = (role == 0) ? Wh0 : (role == 1) ? Wx1 : Wh1;
  const float* Wb = W + (size_t)c0 * HID + kq * 128;  // col c row: Wb + c*HID

  // Epilogue output assignment: 2 outputs per thread, o = 2*tid, 2*tid+1.
  const int o0 = tid * 2;
  const int b1 = o0 >> 4;                    // batch row of outputs
  const int c1 = o0 & 15;                    // local col (even)
  const size_t rb = (size_t)b1 * HID + c0 + c1;

  float bsum0 = 0.f, bsum1 = 0.f;
  if (role == 1) {
    bsum0 = bx1[c0 + c1]     + bh1[c0 + c1];
    bsum1 = bx1[c0 + c1 + 1] + bh1[c0 + c1 + 1];
  }

  for (int i = 0; i < NITER; ++i) {
    bool active;
    const float* src;
    if (role == 0)      { active = (i <= 511);           src = (i == 0) ? h0_init        : h0s[(i-1) & 1]; }
    else if (role == 1) { active = (i >= 1 && i <= 512); src = h0s[(i-1) & 1]; }
    else                { active = (i >= 2 && i <= 513); src = (i == 2) ? (h0_init + NB) : h1s[(i-3) & 1]; }

    if (active) {
      // Prefetch epilogue operands early (all were produced before this iter).
      float e0 = 0.f, e1 = 0.f;
      if (role == 0) {
        e0 = io[(size_t)i * NB + rb];
        e1 = io[(size_t)i * NB + rb + 1];
      } else if (role == 2) {
        const float* ig = ig1s[i & 1];
        e0 = ig[rb];
        e1 = ig[rb + 1];
      }

      const float* hb = src + (size_t)b * HID + kq * 128;  // private K-slice
      float4 hc[8], hn[8];
#pragma unroll
      for (int r = 0; r < 8; ++r) hc[r] = *(const float4*)(hb + r * 4);

      float acc[16];
#pragma unroll
      for (int c = 0; c < 16; ++c) acc[c] = 0.f;

#pragma unroll
      for (int ch = 0; ch < 4; ++ch) {        // 4 chunks x 32 k
        if (ch < 3) {
#pragma unroll
          for (int r = 0; r < 8; ++r)
            hn[r] = *(const float4*)(hb + (ch + 1) * 32 + r * 4);
        }
        const float* Wch = Wb + ch * 32;
#pragma unroll 4
        for (int c = 0; c < 16; ++c) {
          const float* w = Wch + (size_t)c * HID;   // wave-uniform -> s_load
          float s = acc[c];
#pragma unroll
          for (int r = 0; r < 8; ++r) {
            float4 wv = *(const float4*)(w + r * 4);
            s += hc[r].x * wv.x;
            s += hc[r].y * wv.y;
            s += hc[r].z * wv.z;
            s += hc[r].w * wv.w;
          }
          acc[c] = s;
        }
        if (ch < 3) {
#pragma unroll
          for (int r = 0; r < 8; ++r) hc[r] = hn[r];
        }
      }

      // kq-reduction through LDS (row stride 20 words: b128 writes near
      // conflict floor, b32 reads ~2-way).
      float* rrow = &red[(kq * 64 + b) * RSTRIDE];
      *(float4*)(rrow + 0)  = make_float4(acc[0],  acc[1],  acc[2],  acc[3]);
      *(float4*)(rrow + 4)  = make_float4(acc[4],  acc[5],  acc[6],  acc[7]);
      *(float4*)(rrow + 8)  = make_float4(acc[8],  acc[9],  acc[10], acc[11]);
      *(float4*)(rrow + 12) = make_float4(acc[12], acc[13], acc[14], acc[15]);
      __syncthreads();

      float s0 = 0.f, s1 = 0.f;
#pragma unroll
      for (int q = 0; q < 8; ++q) {
        s0 += red[(q * 64 + b1) * RSTRIDE + c1];
        s1 += red[(q * 64 + b1) * RSTRIDE + c1 + 1];
      }

      if (role == 0) {
        float* dst = h0s[i & 1];
        dst[rb]     = tanhf(s0 + e0);
        dst[rb + 1] = tanhf(s1 + e1);
      } else if (role == 1) {
        float* dst = ig1s[(i - 1) & 1];
        dst[rb]     = s0 + bsum0;
        dst[rb + 1] = s1 + bsum1;
      } else {
        const int t = i - 2;
        float* dst = h1s[i & 1];
        float t0 = tanhf(s0 + e0);
        float t1 = tanhf(s1 + e1);
        dst[rb]     = t0;
        dst[rb + 1] = t1;
        io[(size_t)t * NB + rb]     = 10.f * t0;
        io[(size_t)t * NB + rb + 1] = 10.f * t1;
      }
      // red reuse next iter is fenced by gbar's __syncthreads.
    }
    gbar(bar, (unsigned)(NBLK * (i + 1)));
  }
}

// ---------------------------------------------------------------------------
// Kernel C: write h_n = [h0[511], h1[511]] (both live in ping-pong slot 1).
// ---------------------------------------------------------------------------
__global__ __launch_bounds__(256) void finalize_hn(
    const float* __restrict__ ws, float* __restrict__ out)
{
  const int g = blockIdx.x * 256 + threadIdx.x;     // 0..131071
  const float* h0f = ws + NB;                       // h0 slot 1
  const float* h1f = ws + 3 * (size_t)NB;           // h1 slot 1
  const float v = (g < NB) ? h0f[g] : h1f[g - NB];
  out[(size_t)TSEQ * NB + g] = v;
}

// ---------------------------------------------------------------------------
extern "C" void kernel_launch(void* const* d_in, const int* in_sizes, int n_in,
                              void* d_out, int out_size, void* d_ws, size_t ws_size,
                              hipStream_t stream) {
  const float* x  = (const float*)d_in[0];
  const float* h0 = (const float*)d_in[1];
  const float* Wx = (const float*)d_in[2];
  const float* bx = (const float*)d_in[3];
  const float* Wh = (const float*)d_in[4];
  const float* bh = (const float*)d_in[5];
  float* out = (float*)d_out;
  float* ws  = (float*)d_ws;

  igate0_gemm<<<dim3(512 * 16), dim3(256), 0, stream>>>(x, Wx, bx, bh, out, ws);

  float* io = out;
  const float* h0i  = h0;
  const float* pWh0 = Wh;
  const float* pWx1 = Wx + (size_t)HID * HID;
  const float* pWh1 = Wh + (size_t)HID * HID;
  const float* pbx1 = bx + HID;
  const float* pbh1 = bh + HID;
  float* pws = ws;
  void* args[] = { &io, &h0i, &pWh0, &pWx1, &pWh1, &pbx1, &pbh1, &pws };
  hipLaunchCooperativeKernel((const void*)rnn_step, dim3(NBLK), dim3(512),
                             args, 0, stream);

  finalize_hn<<<dim3(512), dim3(256), 0, stream>>>(ws, out);
}